// Round 6
// baseline (2352.348 us; speedup 1.0000x reference)
//
#include <hip/hip_runtime.h>
#include <hip/hip_bf16.h>
#include <math.h>

#define EMB_ATOM 256
#define EMB_EDGE 512
#define K_TOT    1024

typedef __attribute__((ext_vector_type(8))) short bf16x8;
typedef __attribute__((ext_vector_type(4))) float f32x4;
typedef struct { unsigned short x, y, z, w; } us4;

static __device__ __forceinline__ unsigned short f2bf(float f) {
  union { float f; unsigned u; } x; x.f = f;
  unsigned r = x.u + 0x7fffu + ((x.u >> 16) & 1u);   // RTNE
  return (unsigned short)(r >> 16);
}
static __device__ __forceinline__ float bf2f(unsigned short b) {
  union { unsigned u; float f; } x; x.u = ((unsigned)b) << 16; return x.f;
}
static __device__ __forceinline__ us4 f4bf(float4 v) {
  us4 o; o.x = f2bf(v.x); o.y = f2bf(v.y); o.z = f2bf(v.z); o.w = f2bf(v.w); return o;
}
// two float4 chunks -> bf16x8 via v_cvt_pk_bf16_f32 (RTNE)
static __device__ __forceinline__ bf16x8 cvt8(float4 a, float4 b) {
  union { bf16x8 v; __hip_bfloat162 h[4]; } u;
  u.h[0] = __float22bfloat162_rn(make_float2(a.x, a.y));
  u.h[1] = __float22bfloat162_rn(make_float2(a.z, a.w));
  u.h[2] = __float22bfloat162_rn(make_float2(b.x, b.y));
  u.h[3] = __float22bfloat162_rn(make_float2(b.z, b.w));
  return u.v;
}
static __device__ __forceinline__ void gload_lds16(const void* g, void* l) {
  __builtin_amdgcn_global_load_lds(
      (const __attribute__((address_space(1))) unsigned int*)g,
      (__attribute__((address_space(3))) unsigned int*)l, 16, 0, 0);
}
static __device__ __forceinline__ float silu_f(float x) { return x / (1.f + __expf(-x)); }

// ---------------- prep kernels ----------------
__global__ __launch_bounds__(256) void cvt_h_kernel(const float* __restrict__ h,
                                                    unsigned short* __restrict__ hb, int n4) {
  int i = blockIdx.x * 256 + threadIdx.x;
  if (i >= n4) return;
  const float4 v = ((const float4*)h)[i];
  ((us4*)hb)[i] = f4bf(v);
}

// Wt_h: (1024 c, 256 k) bf16, c-major.  c<512: W[k][c]; c>=512: W[256+k][c-512]
__global__ __launch_bounds__(256) void cvt_wh_kernel(const float* __restrict__ W,
                                                     unsigned short* __restrict__ Wt_h) {
  int o = blockIdx.x * 256 + threadIdx.x;    // 1024*256
  int c = o >> 8, k = o & 255;
  float v = (c < 512) ? W[(size_t)k * EMB_EDGE + c]
                      : W[(size_t)(256 + k) * EMB_EDGE + (c - 512)];
  Wt_h[o] = f2bf(v);
}

// Wt_m: (512 c, 512 k) bf16, c-major.  Wt_m[c][k] = W[512+k][c]
__global__ __launch_bounds__(256) void cvt_wm_kernel(const float* __restrict__ W,
                                                     unsigned short* __restrict__ Wt_m) {
  int o = blockIdx.x * 256 + threadIdx.x;    // 512*512
  int c = o >> 9, k = o & 511;
  Wt_m[o] = f2bf(W[(size_t)(512 + k) * EMB_EDGE + c]);
}

// ---------------- H-GEMM: H12 = hb @ [W1|W2]  (N x 1024, bf16) ----------------
__global__ __launch_bounds__(256) void hgemm_kernel(
    const unsigned short* __restrict__ hb,     // (N,256)
    const unsigned short* __restrict__ Wt_h,   // (1024,256) c-major
    unsigned short* __restrict__ H12, int N)
{
  __shared__ unsigned short As[2][128 * 64];
  __shared__ unsigned short Bs[2][128 * 64];
  const int bn = blockIdx.x;       // 0..7
  const int bm = blockIdx.y;
  const int row0 = bm * 128;
  const int tid = threadIdx.x, wave = tid >> 6, lane = tid & 63;
  const int srow = lane >> 3;
  const int schunk = ((lane & 7) ^ srow) * 8;  // pre-swizzled source chunk (elems)

  size_t abase[4]; size_t bbase[4];
#pragma unroll
  for (int i = 0; i < 4; ++i) {
    int r = wave * 32 + i * 8 + srow;
    int e = row0 + r; if (e >= N) e = N - 1;
    abase[i] = (size_t)e * EMB_ATOM;
    bbase[i] = (size_t)(bn * 128 + r) * EMB_ATOM;
  }

  const int wr = wave >> 1, wc = wave & 1, fr = lane & 15, fq = lane >> 4;
  const int fs = fr & 7;

  f32x4 acc[4][4];
#pragma unroll
  for (int m = 0; m < 4; ++m)
#pragma unroll
    for (int n = 0; n < 4; ++n) acc[m][n] = (f32x4)0.f;

#pragma unroll
  for (int i = 0; i < 4; ++i) {
    gload_lds16(hb + abase[i] + schunk,   &As[0][(wave * 32 + i * 8) * 64 + lane * 8]);
    gload_lds16(Wt_h + bbase[i] + schunk, &Bs[0][(wave * 32 + i * 8) * 64 + lane * 8]);
  }
  __syncthreads();

  int cur = 0;
  for (int kt = 0; kt < 4; ++kt) {
    int nxt = cur ^ 1;
    if (kt < 3) {
      int kk = (kt + 1) * 64;
#pragma unroll
      for (int i = 0; i < 4; ++i) {
        gload_lds16(hb + abase[i] + kk + schunk,   &As[nxt][(wave * 32 + i * 8) * 64 + lane * 8]);
        gload_lds16(Wt_h + bbase[i] + kk + schunk, &Bs[nxt][(wave * 32 + i * 8) * 64 + lane * 8]);
      }
    }
#pragma unroll
    for (int ks = 0; ks < 2; ++ks) {
      bf16x8 a[4], b[4];
#pragma unroll
      for (int m = 0; m < 4; ++m)
        a[m] = *(const bf16x8*)(&As[cur][(wr * 64 + m * 16 + fr) * 64 + (((ks * 4 + fq) ^ fs) << 3)]);
#pragma unroll
      for (int n = 0; n < 4; ++n)
        b[n] = *(const bf16x8*)(&Bs[cur][(wc * 64 + n * 16 + fr) * 64 + (((ks * 4 + fq) ^ fs) << 3)]);
#pragma unroll
      for (int m = 0; m < 4; ++m)
#pragma unroll
        for (int n = 0; n < 4; ++n)
          acc[m][n] = __builtin_amdgcn_mfma_f32_16x16x32_bf16(a[m], b[n], acc[m][n], 0, 0, 0);
    }
    __syncthreads();
    cur = nxt;
  }

#pragma unroll
  for (int m = 0; m < 4; ++m) {
    int er0 = row0 + wr * 64 + m * 16 + fq * 4;
#pragma unroll
    for (int n = 0; n < 4; ++n) {
      int col = bn * 128 + wc * 64 + n * 16 + fr;
      f32x4 v = acc[m][n];
#pragma unroll
      for (int j = 0; j < 4; ++j) {
        int e = er0 + j;
        if (e < N) H12[(size_t)e * 1024 + col] = f2bf(v[j]);
      }
    }
  }
}

// ---------------- main GEMM: out = SiLU(m_ij @ W3 + H12[i] + H12[j]) ----------------
// Persistent-B streaming design: whole 128-col B strip (128x512 bf16 = 128KB)
// lives in LDS for the block's lifetime (loaded once, swizzled). Main loop has
// ZERO barriers: each wave builds A fragments directly from global f32 m_ij
// (paired 16B loads fully cover 16 rows x 128B), cvt_pk -> MFMA. 1024 threads
// = 16 waves (4/SIMD), each wave owns a 16x128 output strip per bm-iteration.
__global__ __launch_bounds__(1024, 4) void mgemm_kernel(
    const float* __restrict__ m_ij,
    const int* __restrict__ idx_i,
    const int* __restrict__ idx_j,
    const unsigned short* __restrict__ Wt_m,   // (512 c, 512 k) bf16 c-major
    const unsigned short* __restrict__ H12,    // (N,1024)
    float* __restrict__ out, int E, int ntile, int q)
{
  __shared__ __align__(16) unsigned short Bs[128 * 512];   // 128 KB

  const int id    = blockIdx.x;
  const int group = id >> 2;        // 0..255, contiguous bm chunk
  const int bn    = id & 3;         // 4 siblings adjacent -> co-resident, share A via L3
  const int tid   = threadIdx.x;
  const int wave  = tid >> 6, lane = tid & 63;
  const int fr = lane & 15, fq = lane >> 4;

  // ---- one-time B init: Wt_m strip rows bn*128..+128, swizzled chunks ----
#pragma unroll
  for (int i = 0; i < 8; ++i) {
    int qid = tid + i * 1024;       // 8192 chunks of 16B
    int r = qid >> 6, c = qid & 63;
    bf16x8 v = *(const bf16x8*)(Wt_m + (size_t)(bn * 128 + r) * 512 + c * 8);
    *(bf16x8*)(&Bs[r * 512 + ((c ^ (r & 7)) << 3)]) = v;
  }
  __syncthreads();                  // only barrier in the kernel

  const int t0 = group * q;
  const int t1 = (t0 + q < ntile) ? t0 + q : ntile;

  for (int t = t0; t < t1; ++t) {
    const int row0 = t * 256 + wave * 16;
    int ae = row0 + fr; if (ae >= E) ae = E - 1;
    const float* ap = m_ij + (size_t)ae * EMB_EDGE + fq * 8;

    f32x4 acc[8];
#pragma unroll
    for (int n = 0; n < 8; ++n) acc[n] = (f32x4)0.f;

#pragma unroll
    for (int kt = 0; kt < 16; ++kt) {
      float4 a0 = *(const float4*)(ap + kt * 32);
      float4 a1 = *(const float4*)(ap + kt * 32 + 4);
      bf16x8 af = cvt8(a0, a1);
#pragma unroll
      for (int n = 0; n < 8; ++n) {
        const int r = n * 16 + fr;
        bf16x8 bf = *(const bf16x8*)(&Bs[r * 512 + (((kt * 4 + fq) ^ (r & 7)) << 3)]);
        acc[n] = __builtin_amdgcn_mfma_f32_16x16x32_bf16(af, bf, acc[n], 0, 0, 0);
      }
    }

    // epilogue: gather H12 + SiLU + store
#pragma unroll
    for (int j = 0; j < 4; ++j) {
      int e = row0 + fq * 4 + j;
      if (e < E) {
        const unsigned short* gi = H12 + (size_t)idx_i[e] * 1024 + bn * 128 + fr;
        const unsigned short* gj = H12 + (size_t)idx_j[e] * 1024 + 512 + bn * 128 + fr;
        float* op = out + (size_t)e * EMB_EDGE + bn * 128 + fr;
#pragma unroll
        for (int n = 0; n < 8; ++n) {
          float x = acc[n][j] + bf2f(gi[n * 16]) + bf2f(gj[n * 16]);
          op[n * 16] = silu_f(x);
        }
      }
    }
  }
}

// ---------------- fallback (round-1 fused path, needs only ~27 MB ws) ----------------
__global__ __launch_bounds__(256) void cvt_wt_kernel(const float* __restrict__ W,
                                                     unsigned short* __restrict__ Wt) {
  int o = blockIdx.x * 256 + threadIdx.x;
  int n = o >> 10, k = o & 1023;
  Wt[o] = f2bf(W[(size_t)k * EMB_EDGE + n]);
}

__global__ __launch_bounds__(256) void gemm_gather_kernel(
    const unsigned short* __restrict__ hb,
    const float* __restrict__ m_ij,
    const int* __restrict__ idx_i,
    const int* __restrict__ idx_j,
    const unsigned short* __restrict__ Wt,
    float* __restrict__ out, int E)
{
  __shared__ unsigned short As[128 * 64];
  __shared__ unsigned short Bs[128 * 64];
  const int bn = blockIdx.x, bm = blockIdx.y;
  const int tid = threadIdx.x, wave = tid >> 6, lane = tid & 63;
  const int row0 = bm * 128;
  const int srow = lane >> 3, scol = (lane & 7) * 8;
  int arow[4], aii[4], ajj[4];
#pragma unroll
  for (int i = 0; i < 4; ++i) {
    int r = wave * 32 + i * 8 + srow;
    int e = row0 + r; if (e >= E) e = E - 1;
    arow[i] = r; aii[i] = idx_i[e]; ajj[i] = idx_j[e];
  }
  const int wr = wave >> 1, wc = wave & 1, fr = lane & 15, fq = lane >> 4;
  f32x4 acc[4][4];
#pragma unroll
  for (int m = 0; m < 4; ++m)
#pragma unroll
    for (int n = 0; n < 4; ++n) acc[m][n] = (f32x4)0.f;
  for (int kt = 0; kt < 16; ++kt) {
    __syncthreads();
#pragma unroll
    for (int i = 0; i < 4; ++i) {
      int nl = wave * 32 + i * 8 + srow;
      gload_lds16(Wt + (size_t)(bn * 128 + nl) * K_TOT + kt * 64 + scol, &Bs[nl * 64 + scol]);
    }
    if (kt < 8) {
      const int kh = (kt & 3) * 64;
#pragma unroll
      for (int i = 0; i < 4; ++i) {
        int idx = (kt < 4) ? aii[i] : ajj[i];
        gload_lds16(hb + (size_t)idx * EMB_ATOM + kh + scol, &As[arow[i] * 64 + scol]);
      }
    } else {
      const int kk = (kt - 8) * 64;
#pragma unroll
      for (int it = 0; it < 8; ++it) {
        int flat = it * 1024 + tid * 4;
        int r = flat >> 6, c = flat & 63;
        int e = row0 + r; if (e >= E) e = E - 1;
        const float4 v = *(const float4*)(m_ij + (size_t)e * EMB_EDGE + kk + c);
        *(us4*)(&As[r * 64 + c]) = f4bf(v);
      }
    }
    __syncthreads();
#pragma unroll
    for (int ks = 0; ks < 2; ++ks) {
      bf16x8 a[4], b[4];
#pragma unroll
      for (int m = 0; m < 4; ++m)
        a[m] = *(const bf16x8*)(&As[(wr * 64 + m * 16 + fr) * 64 + ks * 32 + fq * 8]);
#pragma unroll
      for (int n = 0; n < 4; ++n)
        b[n] = *(const bf16x8*)(&Bs[(wc * 64 + n * 16 + fr) * 64 + ks * 32 + fq * 8]);
#pragma unroll
      for (int m = 0; m < 4; ++m)
#pragma unroll
        for (int n = 0; n < 4; ++n)
          acc[m][n] = __builtin_amdgcn_mfma_f32_16x16x32_bf16(a[m], b[n], acc[m][n], 0, 0, 0);
    }
  }
#pragma unroll
  for (int m = 0; m < 4; ++m) {
    int er0 = row0 + wr * 64 + m * 16 + fq * 4;
#pragma unroll
    for (int n = 0; n < 4; ++n) {
      int col = bn * 128 + wc * 64 + n * 16 + fr;
      f32x4 v = acc[m][n];
#pragma unroll
      for (int j = 0; j < 4; ++j) {
        int e = er0 + j;
        if (e < E) out[(size_t)e * EMB_EDGE + col] = silu_f(v[j]);
      }
    }
  }
}

extern "C" void kernel_launch(void* const* d_in, const int* in_sizes, int n_in,
                              void* d_out, int out_size, void* d_ws, size_t ws_size,
                              hipStream_t stream) {
  const float* h    = (const float*)d_in[0];
  const float* m_ij = (const float*)d_in[1];
  const int*   ii   = (const int*)d_in[2];
  const int*   jj   = (const int*)d_in[3];
  const float* W    = (const float*)d_in[4];
  float* out = (float*)d_out;

  const int hsz = in_sizes[0];
  const int N   = hsz / EMB_ATOM;
  const int E   = in_sizes[2];

  unsigned short* hb   = (unsigned short*)d_ws;              // hsz
  unsigned short* Wt_h = hb + hsz;                           // 1024*256
  unsigned short* Wt_m = Wt_h + 1024 * 256;                  // 512*512
  unsigned short* H12  = Wt_m + 512 * 512;                   // N*1024
  size_t need = ((size_t)hsz + 1024 * 256 + 512 * 512 + (size_t)N * 1024) * 2;

  if (ws_size >= need) {
    cvt_h_kernel<<<(hsz / 4 + 255) / 256, 256, 0, stream>>>(h, hb, hsz / 4);
    cvt_wh_kernel<<<1024, 256, 0, stream>>>(W, Wt_h);
    cvt_wm_kernel<<<1024, 256, 0, stream>>>(W, Wt_m);
    int nbmh = (N + 127) / 128;
    hgemm_kernel<<<dim3(8, nbmh), 256, 0, stream>>>(hb, Wt_h, H12, N);
    int ntile = (E + 255) / 256;                 // 256-row tiles
    int q     = (ntile + 255) / 256;             // tiles per group (256 groups)
    mgemm_kernel<<<1024, 1024, 0, stream>>>(m_ij, ii, jj, Wt_m, H12, out, E, ntile, q);
  } else {
    unsigned short* Wt  = (unsigned short*)d_ws;             // 512*1024
    unsigned short* hbf = Wt + 512 * 1024;                   // hsz
    cvt_wt_kernel<<<(512 * 1024) / 256, 256, 0, stream>>>(W, Wt);
    cvt_h_kernel<<<(hsz / 4 + 255) / 256, 256, 0, stream>>>(h, hbf, hsz / 4);
    dim3 grid(4, (E + 127) / 128);
    gemm_gather_kernel<<<grid, 256, 0, stream>>>(hbf, m_ij, ii, jj, Wt, out, E);
  }
}

// Round 7
// 1297.040 us; speedup vs baseline: 1.8136x; 1.8136x over previous
//
#include <hip/hip_runtime.h>
#include <hip/hip_bf16.h>
#include <math.h>

#define EMB_ATOM 256
#define EMB_EDGE 512
#define K_TOT    1024

typedef __attribute__((ext_vector_type(8))) short bf16x8;
typedef __attribute__((ext_vector_type(4))) float f32x4;
typedef struct { unsigned short x, y, z, w; } us4;

static __device__ __forceinline__ unsigned short f2bf(float f) {
  union { float f; unsigned u; } x; x.f = f;
  unsigned r = x.u + 0x7fffu + ((x.u >> 16) & 1u);   // RTNE
  return (unsigned short)(r >> 16);
}
static __device__ __forceinline__ float bf2f(unsigned short b) {
  union { unsigned u; float f; } x; x.u = ((unsigned)b) << 16; return x.f;
}
static __device__ __forceinline__ us4 f4bf(float4 v) {
  us4 o; o.x = f2bf(v.x); o.y = f2bf(v.y); o.z = f2bf(v.z); o.w = f2bf(v.w); return o;
}
// two float4 chunks -> bf16x8 via v_cvt_pk_bf16_f32 (RTNE)
static __device__ __forceinline__ bf16x8 cvt8(float4 a, float4 b) {
  union { bf16x8 v; __hip_bfloat162 h[4]; } u;
  u.h[0] = __float22bfloat162_rn(make_float2(a.x, a.y));
  u.h[1] = __float22bfloat162_rn(make_float2(a.z, a.w));
  u.h[2] = __float22bfloat162_rn(make_float2(b.x, b.y));
  u.h[3] = __float22bfloat162_rn(make_float2(b.z, b.w));
  return u.v;
}
static __device__ __forceinline__ void gload_lds16(const void* g, void* l) {
  __builtin_amdgcn_global_load_lds(
      (const __attribute__((address_space(1))) unsigned int*)g,
      (__attribute__((address_space(3))) unsigned int*)l, 16, 0, 0);
}
static __device__ __forceinline__ float silu_f(float x) { return x / (1.f + __expf(-x)); }

// ---------------- prep kernels ----------------
__global__ __launch_bounds__(256) void cvt_h_kernel(const float* __restrict__ h,
                                                    unsigned short* __restrict__ hb, int n4) {
  int i = blockIdx.x * 256 + threadIdx.x;
  if (i >= n4) return;
  const float4 v = ((const float4*)h)[i];
  ((us4*)hb)[i] = f4bf(v);
}

// Wt_h: (1024 c, 256 k) bf16, c-major.  c<512: W[k][c]; c>=512: W[256+k][c-512]
__global__ __launch_bounds__(256) void cvt_wh_kernel(const float* __restrict__ W,
                                                     unsigned short* __restrict__ Wt_h) {
  int o = blockIdx.x * 256 + threadIdx.x;    // 1024*256
  int c = o >> 8, k = o & 255;
  float v = (c < 512) ? W[(size_t)k * EMB_EDGE + c]
                      : W[(size_t)(256 + k) * EMB_EDGE + (c - 512)];
  Wt_h[o] = f2bf(v);
}

// Wt_m: (512 c, 512 k) bf16, c-major.  Wt_m[c][k] = W[512+k][c]
__global__ __launch_bounds__(256) void cvt_wm_kernel(const float* __restrict__ W,
                                                     unsigned short* __restrict__ Wt_m) {
  int o = blockIdx.x * 256 + threadIdx.x;    // 512*512
  int c = o >> 9, k = o & 511;
  Wt_m[o] = f2bf(W[(size_t)(512 + k) * EMB_EDGE + c]);
}

// ---------------- H-GEMM: H12 = hb @ [W1|W2]  (N x 1024, bf16) ----------------
__global__ __launch_bounds__(256) void hgemm_kernel(
    const unsigned short* __restrict__ hb,     // (N,256)
    const unsigned short* __restrict__ Wt_h,   // (1024,256) c-major
    unsigned short* __restrict__ H12, int N)
{
  __shared__ unsigned short As[2][128 * 64];
  __shared__ unsigned short Bs[2][128 * 64];
  const int bn = blockIdx.x;       // 0..7
  const int bm = blockIdx.y;
  const int row0 = bm * 128;
  const int tid = threadIdx.x, wave = tid >> 6, lane = tid & 63;
  const int srow = lane >> 3;
  const int schunk = ((lane & 7) ^ srow) * 8;  // pre-swizzled source chunk (elems)

  size_t abase[4]; size_t bbase[4];
#pragma unroll
  for (int i = 0; i < 4; ++i) {
    int r = wave * 32 + i * 8 + srow;
    int e = row0 + r; if (e >= N) e = N - 1;
    abase[i] = (size_t)e * EMB_ATOM;
    bbase[i] = (size_t)(bn * 128 + r) * EMB_ATOM;
  }

  const int wr = wave >> 1, wc = wave & 1, fr = lane & 15, fq = lane >> 4;
  const int fs = fr & 7;

  f32x4 acc[4][4];
#pragma unroll
  for (int m = 0; m < 4; ++m)
#pragma unroll
    for (int n = 0; n < 4; ++n) acc[m][n] = (f32x4)0.f;

#pragma unroll
  for (int i = 0; i < 4; ++i) {
    gload_lds16(hb + abase[i] + schunk,   &As[0][(wave * 32 + i * 8) * 64 + lane * 8]);
    gload_lds16(Wt_h + bbase[i] + schunk, &Bs[0][(wave * 32 + i * 8) * 64 + lane * 8]);
  }
  __syncthreads();

  int cur = 0;
  for (int kt = 0; kt < 4; ++kt) {
    int nxt = cur ^ 1;
    if (kt < 3) {
      int kk = (kt + 1) * 64;
#pragma unroll
      for (int i = 0; i < 4; ++i) {
        gload_lds16(hb + abase[i] + kk + schunk,   &As[nxt][(wave * 32 + i * 8) * 64 + lane * 8]);
        gload_lds16(Wt_h + bbase[i] + kk + schunk, &Bs[nxt][(wave * 32 + i * 8) * 64 + lane * 8]);
      }
    }
#pragma unroll
    for (int ks = 0; ks < 2; ++ks) {
      bf16x8 a[4], b[4];
#pragma unroll
      for (int m = 0; m < 4; ++m)
        a[m] = *(const bf16x8*)(&As[cur][(wr * 64 + m * 16 + fr) * 64 + (((ks * 4 + fq) ^ fs) << 3)]);
#pragma unroll
      for (int n = 0; n < 4; ++n)
        b[n] = *(const bf16x8*)(&Bs[cur][(wc * 64 + n * 16 + fr) * 64 + (((ks * 4 + fq) ^ fs) << 3)]);
#pragma unroll
      for (int m = 0; m < 4; ++m)
#pragma unroll
        for (int n = 0; n < 4; ++n)
          acc[m][n] = __builtin_amdgcn_mfma_f32_16x16x32_bf16(a[m], b[n], acc[m][n], 0, 0, 0);
    }
    __syncthreads();
    cur = nxt;
  }

#pragma unroll
  for (int m = 0; m < 4; ++m) {
    int er0 = row0 + wr * 64 + m * 16 + fq * 4;
#pragma unroll
    for (int n = 0; n < 4; ++n) {
      int col = bn * 128 + wc * 64 + n * 16 + fr;
      f32x4 v = acc[m][n];
#pragma unroll
      for (int j = 0; j < 4; ++j) {
        int e = er0 + j;
        if (e < N) H12[(size_t)e * 1024 + col] = f2bf(v[j]);
      }
    }
  }
}

// ---------------- main GEMM: out = SiLU(m_ij @ W3 + H12[i] + H12[j]) ----------------
// Round-4 structure with BK=32: LDS/step = A f32 16KB + B bf16 8KB = 24KB
// -> 6 blocks/CU. Halved per-step staging + doubled resident blocks keeps the
// vmem issue stream continuous through each block's vmcnt(0) barrier drain.
__global__ __launch_bounds__(256, 6) void mgemm_kernel(
    const float* __restrict__ m_ij,
    const int* __restrict__ idx_i,
    const int* __restrict__ idx_j,
    const unsigned short* __restrict__ Wt_m,   // (512,512) c-major
    const unsigned short* __restrict__ H12,    // (N,1024)
    float* __restrict__ out, int E, int nbm)
{
  __shared__ __align__(16) float          As[128 * 32];   // 16KB, 8 chunks/row, XOR r&7
  __shared__ __align__(16) unsigned short Bs[128 * 32];   //  8KB, 4 chunks/row, XOR r&3

  // XCD-pairing map: the 4 bn-blocks of one bm share id%8 -> same XCD (A-panel L2 reuse)
  int b  = blockIdx.x;
  int bm = (b >> 5) * 8 + (b & 7);
  int bn = (b >> 3) & 3;
  if (bm >= nbm) return;
  const int row0 = bm * 128;
  const int tid = threadIdx.x, wave = tid >> 6, lane = tid & 63;
  const int fr = lane & 15, fq = lane >> 4;
  const int wr = wave >> 1, wc = wave & 1;

  // A staging: 4 glds/wave, each 1KB = 8 rows x 128B (32 f32). Source pre-swizzled.
  const float* asrc[4];
#pragma unroll
  for (int i = 0; i < 4; ++i) {
    int r = wave * 32 + i * 8 + (lane >> 3);
    int e = row0 + r; if (e >= E) e = E - 1;
    int sc = (lane & 7) ^ (r & 7);
    asrc[i] = m_ij + (size_t)e * EMB_EDGE + sc * 4;
  }
  // B staging: 2 glds/wave, each 1KB = 16 rows x 64B (32 bf16). Pre-swizzled.
  const unsigned short* bsrc[2];
#pragma unroll
  for (int i = 0; i < 2; ++i) {
    int r = wave * 32 + i * 16 + (lane >> 2);
    int sc = (lane & 3) ^ (r & 3);
    bsrc[i] = Wt_m + (size_t)(bn * 128 + r) * 512 + sc * 8;
  }

  f32x4 acc[4][4];
#pragma unroll
  for (int m = 0; m < 4; ++m)
#pragma unroll
    for (int n = 0; n < 4; ++n) acc[m][n] = (f32x4)0.f;

  for (int kt = 0; kt < 16; ++kt) {
    const int kk = kt * 32;
#pragma unroll
    for (int i = 0; i < 4; ++i)
      gload_lds16(asrc[i] + kk, &As[(wave * 32 + i * 8) * 32]);
#pragma unroll
    for (int i = 0; i < 2; ++i)
      gload_lds16(bsrc[i] + kk, &Bs[(wave * 32 + i * 16) * 32]);
    __syncthreads();   // drains vmcnt -> tiles ready

    {
      bf16x8 bfr[4];
#pragma unroll
      for (int n = 0; n < 4; ++n) {
        const int row = wc * 64 + n * 16 + fr;
        bfr[n] = *(const bf16x8*)(&Bs[row * 32 + ((fq ^ (row & 3)) << 3)]);
      }
#pragma unroll
      for (int m = 0; m < 4; ++m) {
        const int row = wr * 64 + m * 16 + fr;
        const int L0  = fq * 2;
        float4 c0 = *(const float4*)(&As[row * 32 + ((L0 ^ (row & 7)) << 2)]);
        float4 c1 = *(const float4*)(&As[row * 32 + (((L0 + 1) ^ (row & 7)) << 2)]);
        bf16x8 afr = cvt8(c0, c1);
#pragma unroll
        for (int n = 0; n < 4; ++n)
          acc[m][n] = __builtin_amdgcn_mfma_f32_16x16x32_bf16(afr, bfr[n], acc[m][n], 0, 0, 0);
      }
    }
    __syncthreads();   // reads done before restaging
  }

  // epilogue: gather H12 + SiLU + store
#pragma unroll
  for (int m = 0; m < 4; ++m) {
#pragma unroll
    for (int j = 0; j < 4; ++j) {
      int e = row0 + wr * 64 + m * 16 + fq * 4 + j;
      if (e < E) {
        size_t gi = (size_t)idx_i[e] * 1024;
        size_t gj = (size_t)idx_j[e] * 1024 + 512;
#pragma unroll
        for (int n = 0; n < 4; ++n) {
          int col = bn * 128 + wc * 64 + n * 16 + fr;
          float x = acc[m][n][j] + bf2f(H12[gi + col]) + bf2f(H12[gj + col]);
          out[(size_t)e * EMB_EDGE + col] = silu_f(x);
        }
      }
    }
  }
}

// ---------------- fallback (round-1 fused path, needs only ~27 MB ws) ----------------
__global__ __launch_bounds__(256) void cvt_wt_kernel(const float* __restrict__ W,
                                                     unsigned short* __restrict__ Wt) {
  int o = blockIdx.x * 256 + threadIdx.x;
  int n = o >> 10, k = o & 1023;
  Wt[o] = f2bf(W[(size_t)k * EMB_EDGE + n]);
}

__global__ __launch_bounds__(256) void gemm_gather_kernel(
    const unsigned short* __restrict__ hb,
    const float* __restrict__ m_ij,
    const int* __restrict__ idx_i,
    const int* __restrict__ idx_j,
    const unsigned short* __restrict__ Wt,
    float* __restrict__ out, int E)
{
  __shared__ unsigned short As[128 * 64];
  __shared__ unsigned short Bs[128 * 64];
  const int bn = blockIdx.x, bm = blockIdx.y;
  const int tid = threadIdx.x, wave = tid >> 6, lane = tid & 63;
  const int row0 = bm * 128;
  const int srow = lane >> 3, scol = (lane & 7) * 8;
  int arow[4], aii[4], ajj[4];
#pragma unroll
  for (int i = 0; i < 4; ++i) {
    int r = wave * 32 + i * 8 + srow;
    int e = row0 + r; if (e >= E) e = E - 1;
    arow[i] = r; aii[i] = idx_i[e]; ajj[i] = idx_j[e];
  }
  const int wr = wave >> 1, wc = wave & 1, fr = lane & 15, fq = lane >> 4;
  f32x4 acc[4][4];
#pragma unroll
  for (int m = 0; m < 4; ++m)
#pragma unroll
    for (int n = 0; n < 4; ++n) acc[m][n] = (f32x4)0.f;
  for (int kt = 0; kt < 16; ++kt) {
    __syncthreads();
#pragma unroll
    for (int i = 0; i < 4; ++i) {
      int nl = wave * 32 + i * 8 + srow;
      gload_lds16(Wt + (size_t)(bn * 128 + nl) * K_TOT + kt * 64 + scol, &Bs[nl * 64 + scol]);
    }
    if (kt < 8) {
      const int kh = (kt & 3) * 64;
#pragma unroll
      for (int i = 0; i < 4; ++i) {
        int idx = (kt < 4) ? aii[i] : ajj[i];
        gload_lds16(hb + (size_t)idx * EMB_ATOM + kh + scol, &As[arow[i] * 64 + scol]);
      }
    } else {
      const int kk = (kt - 8) * 64;
#pragma unroll
      for (int it = 0; it < 8; ++it) {
        int flat = it * 1024 + tid * 4;
        int r = flat >> 6, c = flat & 63;
        int e = row0 + r; if (e >= E) e = E - 1;
        const float4 v = *(const float4*)(m_ij + (size_t)e * EMB_EDGE + kk + c);
        *(us4*)(&As[r * 64 + c]) = f4bf(v);
      }
    }
    __syncthreads();
#pragma unroll
    for (int ks = 0; ks < 2; ++ks) {
      bf16x8 a[4], b[4];
#pragma unroll
      for (int m = 0; m < 4; ++m)
        a[m] = *(const bf16x8*)(&As[(wr * 64 + m * 16 + fr) * 64 + ks * 32 + fq * 8]);
#pragma unroll
      for (int n = 0; n < 4; ++n)
        b[n] = *(const bf16x8*)(&Bs[(wc * 64 + n * 16 + fr) * 64 + ks * 32 + fq * 8]);
#pragma unroll
      for (int m = 0; m < 4; ++m)
#pragma unroll
        for (int n = 0; n < 4; ++n)
          acc[m][n] = __builtin_amdgcn_mfma_f32_16x16x32_bf16(a[m], b[n], acc[m][n], 0, 0, 0);
    }
  }
#pragma unroll
  for (int m = 0; m < 4; ++m) {
    int er0 = row0 + wr * 64 + m * 16 + fq * 4;
#pragma unroll
    for (int n = 0; n < 4; ++n) {
      int col = bn * 128 + wc * 64 + n * 16 + fr;
      f32x4 v = acc[m][n];
#pragma unroll
      for (int j = 0; j < 4; ++j) {
        int e = er0 + j;
        if (e < E) out[(size_t)e * EMB_EDGE + col] = silu_f(v[j]);
      }
    }
  }
}

extern "C" void kernel_launch(void* const* d_in, const int* in_sizes, int n_in,
                              void* d_out, int out_size, void* d_ws, size_t ws_size,
                              hipStream_t stream) {
  const float* h    = (const float*)d_in[0];
  const float* m_ij = (const float*)d_in[1];
  const int*   ii   = (const int*)d_in[2];
  const int*   jj   = (const int*)d_in[3];
  const float* W    = (const float*)d_in[4];
  float* out = (float*)d_out;

  const int hsz = in_sizes[0];
  const int N   = hsz / EMB_ATOM;
  const int E   = in_sizes[2];

  unsigned short* hb   = (unsigned short*)d_ws;              // hsz
  unsigned short* Wt_h = hb + hsz;                           // 1024*256
  unsigned short* Wt_m = Wt_h + 1024 * 256;                  // 512*512
  unsigned short* H12  = Wt_m + 512 * 512;                   // N*1024
  size_t need = ((size_t)hsz + 1024 * 256 + 512 * 512 + (size_t)N * 1024) * 2;

  if (ws_size >= need) {
    cvt_h_kernel<<<(hsz / 4 + 255) / 256, 256, 0, stream>>>(h, hb, hsz / 4);
    cvt_wh_kernel<<<1024, 256, 0, stream>>>(W, Wt_h);
    cvt_wm_kernel<<<1024, 256, 0, stream>>>(W, Wt_m);
    int nbmh = (N + 127) / 128;
    hgemm_kernel<<<dim3(8, nbmh), 256, 0, stream>>>(hb, Wt_h, H12, N);
    int nbm  = (E + 127) / 128;
    int ngrp = (nbm + 7) / 8;
    mgemm_kernel<<<ngrp * 32, 256, 0, stream>>>(m_ij, ii, jj, Wt_m, H12, out, E, nbm);
  } else {
    unsigned short* Wt  = (unsigned short*)d_ws;             // 512*1024
    unsigned short* hbf = Wt + 512 * 1024;                   // hsz
    cvt_wt_kernel<<<(512 * 1024) / 256, 256, 0, stream>>>(W, Wt);
    cvt_h_kernel<<<(hsz / 4 + 255) / 256, 256, 0, stream>>>(h, hbf, hsz / 4);
    dim3 grid(4, (E + 127) / 128);
    gemm_gather_kernel<<<grid, 256, 0, stream>>>(hbf, m_ij, ii, jj, Wt, out, E);
  }
}

// Round 8
// 470.172 us; speedup vs baseline: 5.0032x; 2.7586x over previous
//
#include <hip/hip_runtime.h>
#include <hip/hip_bf16.h>
#include <math.h>

#define EMB_ATOM 256
#define EMB_EDGE 512
#define K_TOT    1024

typedef __attribute__((ext_vector_type(8))) short bf16x8;
typedef __attribute__((ext_vector_type(4))) float f32x4;
typedef struct { unsigned short x, y, z, w; } us4;

static __device__ __forceinline__ unsigned short f2bf(float f) {
  union { float f; unsigned u; } x; x.f = f;
  unsigned r = x.u + 0x7fffu + ((x.u >> 16) & 1u);   // RTNE
  return (unsigned short)(r >> 16);
}
static __device__ __forceinline__ float bf2f(unsigned short b) {
  union { unsigned u; float f; } x; x.u = ((unsigned)b) << 16; return x.f;
}
static __device__ __forceinline__ us4 f4bf(float4 v) {
  us4 o; o.x = f2bf(v.x); o.y = f2bf(v.y); o.z = f2bf(v.z); o.w = f2bf(v.w); return o;
}
// two float4 chunks -> bf16x8 via v_cvt_pk_bf16_f32 (RTNE)
static __device__ __forceinline__ bf16x8 cvt8(float4 a, float4 b) {
  union { bf16x8 v; __hip_bfloat162 h[4]; } u;
  u.h[0] = __float22bfloat162_rn(make_float2(a.x, a.y));
  u.h[1] = __float22bfloat162_rn(make_float2(a.z, a.w));
  u.h[2] = __float22bfloat162_rn(make_float2(b.x, b.y));
  u.h[3] = __float22bfloat162_rn(make_float2(b.z, b.w));
  return u.v;
}
static __device__ __forceinline__ void gload_lds16(const void* g, void* l) {
  __builtin_amdgcn_global_load_lds(
      (const __attribute__((address_space(1))) unsigned int*)g,
      (__attribute__((address_space(3))) unsigned int*)l, 16, 0, 0);
}
static __device__ __forceinline__ float silu_f(float x) { return x / (1.f + __expf(-x)); }

// ---------------- prep kernels ----------------
__global__ __launch_bounds__(256) void cvt_h_kernel(const float* __restrict__ h,
                                                    unsigned short* __restrict__ hb, int n4) {
  int i = blockIdx.x * 256 + threadIdx.x;
  if (i >= n4) return;
  const float4 v = ((const float4*)h)[i];
  ((us4*)hb)[i] = f4bf(v);
}

// Wt_h: (1024 c, 256 k) bf16, c-major.  c<512: W[k][c]; c>=512: W[256+k][c-512]
__global__ __launch_bounds__(256) void cvt_wh_kernel(const float* __restrict__ W,
                                                     unsigned short* __restrict__ Wt_h) {
  int o = blockIdx.x * 256 + threadIdx.x;    // 1024*256
  int c = o >> 8, k = o & 255;
  float v = (c < 512) ? W[(size_t)k * EMB_EDGE + c]
                      : W[(size_t)(256 + k) * EMB_EDGE + (c - 512)];
  Wt_h[o] = f2bf(v);
}

// Wt_m: (512 c, 512 k) bf16, c-major.  Wt_m[c][k] = W[512+k][c]
__global__ __launch_bounds__(256) void cvt_wm_kernel(const float* __restrict__ W,
                                                     unsigned short* __restrict__ Wt_m) {
  int o = blockIdx.x * 256 + threadIdx.x;    // 512*512
  int c = o >> 9, k = o & 511;
  Wt_m[o] = f2bf(W[(size_t)(512 + k) * EMB_EDGE + c]);
}

// ---------------- H-GEMM: H12 = hb @ [W1|W2]  (N x 1024, bf16) ----------------
__global__ __launch_bounds__(256) void hgemm_kernel(
    const unsigned short* __restrict__ hb,     // (N,256)
    const unsigned short* __restrict__ Wt_h,   // (1024,256) c-major
    unsigned short* __restrict__ H12, int N)
{
  __shared__ unsigned short As[2][128 * 64];
  __shared__ unsigned short Bs[2][128 * 64];
  const int bn = blockIdx.x;       // 0..7
  const int bm = blockIdx.y;
  const int row0 = bm * 128;
  const int tid = threadIdx.x, wave = tid >> 6, lane = tid & 63;
  const int srow = lane >> 3;
  const int schunk = ((lane & 7) ^ srow) * 8;  // pre-swizzled source chunk (elems)

  size_t abase[4]; size_t bbase[4];
#pragma unroll
  for (int i = 0; i < 4; ++i) {
    int r = wave * 32 + i * 8 + srow;
    int e = row0 + r; if (e >= N) e = N - 1;
    abase[i] = (size_t)e * EMB_ATOM;
    bbase[i] = (size_t)(bn * 128 + r) * EMB_ATOM;
  }

  const int wr = wave >> 1, wc = wave & 1, fr = lane & 15, fq = lane >> 4;
  const int fs = fr & 7;

  f32x4 acc[4][4];
#pragma unroll
  for (int m = 0; m < 4; ++m)
#pragma unroll
    for (int n = 0; n < 4; ++n) acc[m][n] = (f32x4)0.f;

#pragma unroll
  for (int i = 0; i < 4; ++i) {
    gload_lds16(hb + abase[i] + schunk,   &As[0][(wave * 32 + i * 8) * 64 + lane * 8]);
    gload_lds16(Wt_h + bbase[i] + schunk, &Bs[0][(wave * 32 + i * 8) * 64 + lane * 8]);
  }
  __syncthreads();

  int cur = 0;
  for (int kt = 0; kt < 4; ++kt) {
    int nxt = cur ^ 1;
    if (kt < 3) {
      int kk = (kt + 1) * 64;
#pragma unroll
      for (int i = 0; i < 4; ++i) {
        gload_lds16(hb + abase[i] + kk + schunk,   &As[nxt][(wave * 32 + i * 8) * 64 + lane * 8]);
        gload_lds16(Wt_h + bbase[i] + kk + schunk, &Bs[nxt][(wave * 32 + i * 8) * 64 + lane * 8]);
      }
    }
#pragma unroll
    for (int ks = 0; ks < 2; ++ks) {
      bf16x8 a[4], b[4];
#pragma unroll
      for (int m = 0; m < 4; ++m)
        a[m] = *(const bf16x8*)(&As[cur][(wr * 64 + m * 16 + fr) * 64 + (((ks * 4 + fq) ^ fs) << 3)]);
#pragma unroll
      for (int n = 0; n < 4; ++n)
        b[n] = *(const bf16x8*)(&Bs[cur][(wc * 64 + n * 16 + fr) * 64 + (((ks * 4 + fq) ^ fs) << 3)]);
#pragma unroll
      for (int m = 0; m < 4; ++m)
#pragma unroll
        for (int n = 0; n < 4; ++n)
          acc[m][n] = __builtin_amdgcn_mfma_f32_16x16x32_bf16(a[m], b[n], acc[m][n], 0, 0, 0);
    }
    __syncthreads();
    cur = nxt;
  }

#pragma unroll
  for (int m = 0; m < 4; ++m) {
    int er0 = row0 + wr * 64 + m * 16 + fq * 4;
#pragma unroll
    for (int n = 0; n < 4; ++n) {
      int col = bn * 128 + wc * 64 + n * 16 + fr;
      f32x4 v = acc[m][n];
#pragma unroll
      for (int j = 0; j < 4; ++j) {
        int e = er0 + j;
        if (e < N) H12[(size_t)e * 1024 + col] = f2bf(v[j]);
      }
    }
  }
}

// ---------------- main GEMM: out = SiLU(m_ij @ W3 + H12[i] + H12[j]) ----------------
// BM=128, BN=256 (2 col strips -> A staged 2x not 4x), BK=32, double-buffered,
// one barrier/step, stage(kt+1) issued BEFORE compute(kt). 512 threads (8 waves,
// 2x4), per-wave 64x64 (acc[4][4]=64 VGPR), launch_bounds(512,4) -> 128 VGPR
// budget. LDS = 2*(16K A + 16K B) = 64KB -> 2 blocks/CU.
__global__ __launch_bounds__(512, 4) void mgemm_kernel(
    const float* __restrict__ m_ij,
    const int* __restrict__ idx_i,
    const int* __restrict__ idx_j,
    const unsigned short* __restrict__ Wt_m,   // (512,512) c-major
    const unsigned short* __restrict__ H12,    // (N,1024)
    float* __restrict__ out, int E, int nbm)
{
  __shared__ __align__(16) float          As[2][128 * 32];   // 2 x 16KB, 8 chunks/row XOR r&7
  __shared__ __align__(16) unsigned short Bs[2][256 * 32];   // 2 x 16KB, 4 chunks/row XOR r&3

  // XCD map: both bn-strips of a bm share id%8 -> same XCD (A-panel L2 reuse)
  int b  = blockIdx.x;
  int bm = (b & 7) + (b >> 4) * 8;
  int bn = (b >> 3) & 1;
  if (bm >= nbm) return;
  const int row0 = bm * 128;
  const int tid = threadIdx.x, wave = tid >> 6, lane = tid & 63;
  const int fr = lane & 15, fq = lane >> 4;
  const int wr = wave >> 2, wc = wave & 3;

  // staging geometry: 2 rounds each; flat = i*512 + tid
  const float* asrc[2];
  const unsigned short* bsrc[2];
#pragma unroll
  for (int i = 0; i < 2; ++i) {
    int flat = i * 512 + tid;
    int ar = flat >> 3, ac = flat & 7;           // A: 128 rows x 8 chunks (16B) of f32
    int e = row0 + ar; if (e >= E) e = E - 1;
    asrc[i] = m_ij + (size_t)e * EMB_EDGE + ((ac ^ (ar & 7)) << 2);
    int br = flat >> 2, bc = flat & 3;           // B: 256 rows x 4 chunks (16B) of bf16
    bsrc[i] = Wt_m + (size_t)(bn * 256 + br) * 512 + ((bc ^ (br & 3)) << 3);
  }
  const unsigned abase = wave * 64 * 4;          // f32 elems: (i*512+wave*64)*16B
  const unsigned bbase = wave * 64 * 8;          // bf16 elems

  f32x4 acc[4][4];
#pragma unroll
  for (int m = 0; m < 4; ++m)
#pragma unroll
    for (int n = 0; n < 4; ++n) acc[m][n] = (f32x4)0.f;

  // prologue: stage kt=0 into buf 0
#pragma unroll
  for (int i = 0; i < 2; ++i) {
    gload_lds16(asrc[i], &As[0][i * 512 * 4 + abase]);
    gload_lds16(bsrc[i], &Bs[0][i * 512 * 8 + bbase]);
  }
  __syncthreads();

  for (int kt = 0; kt < 16; ++kt) {
    const int cur = kt & 1;
    if (kt < 15) {
      const int kk = (kt + 1) * 32;
#pragma unroll
      for (int i = 0; i < 2; ++i) {
        gload_lds16(asrc[i] + kk, &As[cur ^ 1][i * 512 * 4 + abase]);
        gload_lds16(bsrc[i] + kk, &Bs[cur ^ 1][i * 512 * 8 + bbase]);
      }
    }
    // compute on buf cur
    bf16x8 bfr[4];
#pragma unroll
    for (int n = 0; n < 4; ++n) {
      const int row = wc * 64 + n * 16 + fr;
      bfr[n] = *(const bf16x8*)(&Bs[cur][row * 32 + ((fq ^ (row & 3)) << 3)]);
    }
#pragma unroll
    for (int m = 0; m < 4; ++m) {
      const int row = wr * 64 + m * 16 + fr;
      float4 c0 = *(const float4*)(&As[cur][row * 32 + (((fq * 2) ^ (row & 7)) << 2)]);
      float4 c1 = *(const float4*)(&As[cur][row * 32 + (((fq * 2 + 1) ^ (row & 7)) << 2)]);
      bf16x8 afr = cvt8(c0, c1);
#pragma unroll
      for (int n = 0; n < 4; ++n)
        acc[m][n] = __builtin_amdgcn_mfma_f32_16x16x32_bf16(afr, bfr[n], acc[m][n], 0, 0, 0);
    }
    __syncthreads();   // drains next-buf loads (flew under compute); fences reuse
  }

  // epilogue: gather H12 + SiLU + store
#pragma unroll
  for (int m = 0; m < 4; ++m) {
#pragma unroll
    for (int j = 0; j < 4; ++j) {
      int e = row0 + wr * 64 + m * 16 + fq * 4 + j;
      if (e < E) {
        size_t gi = (size_t)idx_i[e] * 1024;
        size_t gj = (size_t)idx_j[e] * 1024 + 512;
#pragma unroll
        for (int n = 0; n < 4; ++n) {
          int col = bn * 256 + wc * 64 + n * 16 + fr;
          float x = acc[m][n][j] + bf2f(H12[gi + col]) + bf2f(H12[gj + col]);
          out[(size_t)e * EMB_EDGE + col] = silu_f(x);
        }
      }
    }
  }
}

// ---------------- fallback (round-1 fused path, needs only ~27 MB ws) ----------------
__global__ __launch_bounds__(256) void cvt_wt_kernel(const float* __restrict__ W,
                                                     unsigned short* __restrict__ Wt) {
  int o = blockIdx.x * 256 + threadIdx.x;
  int n = o >> 10, k = o & 1023;
  Wt[o] = f2bf(W[(size_t)k * EMB_EDGE + n]);
}

__global__ __launch_bounds__(256) void gemm_gather_kernel(
    const unsigned short* __restrict__ hb,
    const float* __restrict__ m_ij,
    const int* __restrict__ idx_i,
    const int* __restrict__ idx_j,
    const unsigned short* __restrict__ Wt,
    float* __restrict__ out, int E)
{
  __shared__ unsigned short As[128 * 64];
  __shared__ unsigned short Bs[128 * 64];
  const int bn = blockIdx.x, bm = blockIdx.y;
  const int tid = threadIdx.x, wave = tid >> 6, lane = tid & 63;
  const int row0 = bm * 128;
  const int srow = lane >> 3, scol = (lane & 7) * 8;
  int arow[4], aii[4], ajj[4];
#pragma unroll
  for (int i = 0; i < 4; ++i) {
    int r = wave * 32 + i * 8 + srow;
    int e = row0 + r; if (e >= E) e = E - 1;
    arow[i] = r; aii[i] = idx_i[e]; ajj[i] = idx_j[e];
  }
  const int wr = wave >> 1, wc = wave & 1, fr = lane & 15, fq = lane >> 4;
  f32x4 acc[4][4];
#pragma unroll
  for (int m = 0; m < 4; ++m)
#pragma unroll
    for (int n = 0; n < 4; ++n) acc[m][n] = (f32x4)0.f;
  for (int kt = 0; kt < 16; ++kt) {
    __syncthreads();
#pragma unroll
    for (int i = 0; i < 4; ++i) {
      int nl = wave * 32 + i * 8 + srow;
      gload_lds16(Wt + (size_t)(bn * 128 + nl) * K_TOT + kt * 64 + scol, &Bs[nl * 64 + scol]);
    }
    if (kt < 8) {
      const int kh = (kt & 3) * 64;
#pragma unroll
      for (int i = 0; i < 4; ++i) {
        int idx = (kt < 4) ? aii[i] : ajj[i];
        gload_lds16(hb + (size_t)idx * EMB_ATOM + kh + scol, &As[arow[i] * 64 + scol]);
      }
    } else {
      const int kk = (kt - 8) * 64;
#pragma unroll
      for (int it = 0; it < 8; ++it) {
        int flat = it * 1024 + tid * 4;
        int r = flat >> 6, c = flat & 63;
        int e = row0 + r; if (e >= E) e = E - 1;
        const float4 v = *(const float4*)(m_ij + (size_t)e * EMB_EDGE + kk + c);
        *(us4*)(&As[r * 64 + c]) = f4bf(v);
      }
    }
    __syncthreads();
#pragma unroll
    for (int ks = 0; ks < 2; ++ks) {
      bf16x8 a[4], b[4];
#pragma unroll
      for (int m = 0; m < 4; ++m)
        a[m] = *(const bf16x8*)(&As[(wr * 64 + m * 16 + fr) * 64 + ks * 32 + fq * 8]);
#pragma unroll
      for (int n = 0; n < 4; ++n)
        b[n] = *(const bf16x8*)(&Bs[(wc * 64 + n * 16 + fr) * 64 + ks * 32 + fq * 8]);
#pragma unroll
      for (int m = 0; m < 4; ++m)
#pragma unroll
        for (int n = 0; n < 4; ++n)
          acc[m][n] = __builtin_amdgcn_mfma_f32_16x16x32_bf16(a[m], b[n], acc[m][n], 0, 0, 0);
    }
  }
#pragma unroll
  for (int m = 0; m < 4; ++m) {
    int er0 = row0 + wr * 64 + m * 16 + fq * 4;
#pragma unroll
    for (int n = 0; n < 4; ++n) {
      int col = bn * 128 + wc * 64 + n * 16 + fr;
      f32x4 v = acc[m][n];
#pragma unroll
      for (int j = 0; j < 4; ++j) {
        int e = er0 + j;
        if (e < E) out[(size_t)e * EMB_EDGE + col] = silu_f(v[j]);
      }
    }
  }
}

extern "C" void kernel_launch(void* const* d_in, const int* in_sizes, int n_in,
                              void* d_out, int out_size, void* d_ws, size_t ws_size,
                              hipStream_t stream) {
  const float* h    = (const float*)d_in[0];
  const float* m_ij = (const float*)d_in[1];
  const int*   ii   = (const int*)d_in[2];
  const int*   jj   = (const int*)d_in[3];
  const float* W    = (const float*)d_in[4];
  float* out = (float*)d_out;

  const int hsz = in_sizes[0];
  const int N   = hsz / EMB_ATOM;
  const int E   = in_sizes[2];

  unsigned short* hb   = (unsigned short*)d_ws;              // hsz
  unsigned short* Wt_h = hb + hsz;                           // 1024*256
  unsigned short* Wt_m = Wt_h + 1024 * 256;                  // 512*512
  unsigned short* H12  = Wt_m + 512 * 512;                   // N*1024
  size_t need = ((size_t)hsz + 1024 * 256 + 512 * 512 + (size_t)N * 1024) * 2;

  if (ws_size >= need) {
    cvt_h_kernel<<<(hsz / 4 + 255) / 256, 256, 0, stream>>>(h, hb, hsz / 4);
    cvt_wh_kernel<<<1024, 256, 0, stream>>>(W, Wt_h);
    cvt_wm_kernel<<<1024, 256, 0, stream>>>(W, Wt_m);
    int nbmh = (N + 127) / 128;
    hgemm_kernel<<<dim3(8, nbmh), 256, 0, stream>>>(hb, Wt_h, H12, N);
    int nbm  = (E + 127) / 128;
    int ngrp = (nbm + 7) / 8;
    mgemm_kernel<<<ngrp * 16, 512, 0, stream>>>(m_ij, ii, jj, Wt_m, H12, out, E, nbm);
  } else {
    unsigned short* Wt  = (unsigned short*)d_ws;             // 512*1024
    unsigned short* hbf = Wt + 512 * 1024;                   // hsz
    cvt_wt_kernel<<<(512 * 1024) / 256, 256, 0, stream>>>(W, Wt);
    cvt_h_kernel<<<(hsz / 4 + 255) / 256, 256, 0, stream>>>(h, hbf, hsz / 4);
    dim3 grid(4, (E + 127) / 128);
    gemm_gather_kernel<<<grid, 256, 0, stream>>>(hbf, m_ij, ii, jj, Wt, out, E);
  }
}